// Round 1
// baseline (353.767 us; speedup 1.0000x reference)
//
#include <hip/hip_runtime.h>

// Problem constants
constexpr int SL  = 2048;  // sequence length T
constexpr int NB  = 2;     // batch
constexpr int NH  = 16;    // q heads
constexpr int NKV = 4;     // kv heads
constexpr int HDIM = 128;  // head dim
constexpr int DM  = 2048;  // model dim

typedef unsigned short u16;
typedef unsigned int   u32;
typedef short s16x8 __attribute__((ext_vector_type(8)));
typedef float f32x4 __attribute__((ext_vector_type(4)));

__device__ inline u16 f2bf(float x) {
  union { float f; u32 u; } c; c.f = x;
  u32 r = c.u + 0x7fffu + ((c.u >> 16) & 1u);
  return (u16)(r >> 16);
}

__device__ inline void gload16(const void* g, void* l) {
  __builtin_amdgcn_global_load_lds((const __attribute__((address_space(1))) void*)g,
                                   (__attribute__((address_space(3))) void*)l, 16, 0, 0);
}

// ---------------- x f32 -> bf16 ----------------
__global__ __launch_bounds__(256) void cvt_x(const float* __restrict__ x, u16* __restrict__ xb) {
  long i = ((long)blockIdx.x * 256 + threadIdx.x) * 8;
  float4 a = *(const float4*)(x + i);
  float4 b = *(const float4*)(x + i + 4);
  uint4 ov;
  ov.x = (u32)f2bf(a.x) | ((u32)f2bf(a.y) << 16);
  ov.y = (u32)f2bf(a.z) | ((u32)f2bf(a.w) << 16);
  ov.z = (u32)f2bf(b.x) | ((u32)f2bf(b.y) << 16);
  ov.w = (u32)f2bf(b.z) | ((u32)f2bf(b.w) << 16);
  *(uint4*)(xb + i) = ov;
}

// ---------------- weight transpose f32 KxN -> bf16 NxK ----------------
__global__ __launch_bounds__(256) void wtrans(const float* __restrict__ src, u16* __restrict__ dst,
                                              int K, int N) {
  __shared__ float ld[64][65];
  int tid = threadIdx.x;
  long c0 = (long)blockIdx.x * 64;  // N-dim tile
  long r0 = (long)blockIdx.y * 64;  // K-dim tile
  for (int i = 0; i < 16; ++i) {
    int e = tid + 256 * i;
    int r = e >> 6, c = e & 63;
    ld[r][c] = src[(r0 + r) * N + c0 + c];
  }
  __syncthreads();
  for (int i = 0; i < 16; ++i) {
    int e = tid + 256 * i;
    int r = e >> 6, c = e & 63;
    dst[(c0 + r) * K + r0 + c] = f2bf(ld[c][r]);
  }
}

// ---------------- rope tables (f32, accurate trig) ----------------
__global__ void rope_tab(float* __restrict__ rc, float* __restrict__ rs) {
  int i = blockIdx.x * 256 + threadIdx.x;  // 2048*64
  int t = i >> 6, f = i & 63;
  float inv = expf(-(float)f * (9.210340371976184f / 64.0f));  // 10000^(-f/64)
  float ang = (float)t * inv;
  rc[i] = cosf(ang);
  rs[i] = sinf(ang);
}

// ---------------- GEMM: C[M][N] f32 = A[M][K]bf16 * BT[N][K]bf16^T ----------------
// 128x128 tile, BK=64, 4 waves (2x2), mfma 16x16x32, global_load_lds staging,
// XOR-swizzled LDS (G4): LDS[row][colByte ^ ((row&7)<<4)], pre-swizzled source.
__global__ __launch_bounds__(256) void gemm_bt(const u16* __restrict__ A,
                                               const u16* __restrict__ BT,
                                               float* __restrict__ C,
                                               int M, int N, int K) {
  __shared__ __align__(16) char As[128 * 128];
  __shared__ __align__(16) char Bs[128 * 128];
  const int tid = threadIdx.x;
  const int lane = tid & 63;
  const int w = tid >> 6;
  const int wm = w >> 1, wn = w & 1;
  const int lr = lane & 15, lg = lane >> 4;
  const long bm = (long)blockIdx.x * 128;
  const long bn = (long)blockIdx.y * 128;

  f32x4 acc[4][4] = {};

  for (int kt = 0; kt < K; kt += 64) {
    __syncthreads();
#pragma unroll
    for (int i = 0; i < 4; ++i) {
      int c = tid + 256 * i;
      int row = c >> 3;
      int slot = (c & 7) << 4;
      int gs = slot ^ ((row & 7) << 4);
      gload16(A + (bm + row) * K + kt + (gs >> 1), As + c * 16);
    }
#pragma unroll
    for (int i = 0; i < 4; ++i) {
      int c = tid + 256 * i;
      int row = c >> 3;
      int slot = (c & 7) << 4;
      int gs = slot ^ ((row & 7) << 4);
      gload16(BT + (bn + row) * K + kt + (gs >> 1), Bs + c * 16);
    }
    asm volatile("s_waitcnt vmcnt(0)" ::: "memory");
    __syncthreads();

#pragma unroll
    for (int kk = 0; kk < 2; ++kk) {
      int colB = (kk * 32 + lg * 8) * 2;
      s16x8 af[4], bfv[4];
#pragma unroll
      for (int m = 0; m < 4; ++m) {
        int row = wm * 64 + m * 16 + lr;
        af[m] = *(const s16x8*)(As + row * 128 + (colB ^ ((row & 7) << 4)));
      }
#pragma unroll
      for (int n = 0; n < 4; ++n) {
        int row = wn * 64 + n * 16 + lr;
        bfv[n] = *(const s16x8*)(Bs + row * 128 + (colB ^ ((row & 7) << 4)));
      }
#pragma unroll
      for (int m = 0; m < 4; ++m)
#pragma unroll
        for (int n = 0; n < 4; ++n)
          acc[m][n] = __builtin_amdgcn_mfma_f32_16x16x32_bf16(af[m], bfv[n], acc[m][n], 0, 0, 0);
    }
  }

#pragma unroll
  for (int m = 0; m < 4; ++m)
#pragma unroll
    for (int n = 0; n < 4; ++n) {
      long row = bm + wm * 64 + m * 16 + lg * 4;
      long col = bn + wn * 64 + n * 16 + lr;
      float* cp = C + row * N + col;
#pragma unroll
      for (int r = 0; r < 4; ++r) cp[(long)r * N] = acc[m][n][r];
    }
}

// ---------------- RMSNorm + RoPE + gain; write q/k bf16 head-major ----------------
__global__ __launch_bounds__(256) void normrope(const float* __restrict__ qkv,
                                                const float* __restrict__ rc,
                                                const float* __restrict__ rs,
                                                const float* __restrict__ qg,
                                                u16* __restrict__ qb, u16* __restrict__ kb) {
  int token = blockIdx.x;            // b*SL + t
  int b = token >> 11, t = token & (SL - 1);
  int lane = threadIdx.x & 63, w = threadIdx.x >> 6;
  const float* row = qkv + (long)token * 3072;
  float c = rc[t * 64 + lane], s = rs[t * 64 + lane];
  for (int slot = w; slot < 20; slot += 4) {  // 0..15 q heads, 16..19 k heads
    const float* p = row + slot * 128;
    float v0 = p[lane], v1 = p[lane + 64];
    float ss = v0 * v0 + v1 * v1;
    for (int m = 1; m < 64; m <<= 1) ss += __shfl_xor(ss, m);
    float rms = rsqrtf(ss * (1.0f / 128.0f) + 1.1920929e-07f);
    v0 *= rms; v1 *= rms;
    float o0 =  v0 * c + v1 * s;
    float o1 = -v0 * s + v1 * c;
    u16* dst;
    if (slot < 16) {
      float g = qg[slot];
      o0 *= g; o1 *= g;
      dst = qb + ((long)(b * NH + slot) * SL + t) * 128;
    } else {
      dst = kb + ((long)(b * NKV + (slot - 16)) * SL + t) * 128;
    }
    dst[lane] = f2bf(o0);
    dst[lane + 64] = f2bf(o1);
  }
}

// ---------------- V transpose: qkv f32 v-cols -> vt bf16 [b][kvh][d][t] ----------------
__global__ __launch_bounds__(256) void vtrans(const float* __restrict__ qkv, u16* __restrict__ vt) {
  __shared__ float ld[64][129];
  int blk = blockIdx.x;              // (b*NKV + kvh)*32 + ttile
  int tt = blk & 31, kvb = blk >> 5;
  int tid = threadIdx.x;
  const float* src = qkv + (long)(((kvb >> 2) * SL) + tt * 64) * 3072 + 2560 + (kvb & 3) * 128;
  for (int i = 0; i < 32; ++i) {
    int e = tid + 256 * i;           // 64 rows x 128 d
    int r = e >> 7, d = e & 127;
    ld[r][d] = src[(long)r * 3072 + d];
  }
  __syncthreads();
  u16* dst = vt + (long)kvb * 128 * SL + tt * 64;
  for (int i = 0; i < 32; ++i) {
    int o = tid + 256 * i;
    int d = o >> 6, r = o & 63;
    dst[(long)d * SL + r] = f2bf(ld[r][d]);
  }
}

// ---------------- flash attention (causal, GQA) ----------------
// grid (SL/64, NB*NH), 256 thr. Q tile 64 rows (16/wave), KV tiles 64.
__global__ __launch_bounds__(256) void attn(const u16* __restrict__ qb, const u16* __restrict__ kb,
                                            const u16* __restrict__ vt, float* __restrict__ yg) {
  __shared__ __align__(16) char Ks[64 * 256];   // [kv][d] rows 256B, swizzled
  __shared__ __align__(16) char Vs[128 * 128];  // [d][kv] rows 128B, swizzled
  __shared__ __align__(16) char Ps[64 * 128];   // [q][kv] bf16 rows 128B, swizzled
  const int tid = threadIdx.x, lane = tid & 63, w = tid >> 6;
  const int qblk = blockIdx.x;
  const int bh = blockIdx.y;
  const int b = bh >> 4, h = bh & 15;
  const int kvh = h >> 2;
  const int lr = lane & 15, lg = lane >> 4;

  const u16* qp = qb + ((long)bh * SL + qblk * 64 + w * 16 + lr) * 128;
  s16x8 qf[4];
#pragma unroll
  for (int kk = 0; kk < 4; ++kk) qf[kk] = *(const s16x8*)(qp + kk * 32 + lg * 8);

  f32x4 acc[8] = {};
  float m_run[4], l_run[4];
#pragma unroll
  for (int r = 0; r < 4; ++r) { m_run[r] = -1e30f; l_run[r] = 0.f; }

  const u16* kbase = kb + (long)(b * NKV + kvh) * SL * 128;
  const u16* vbase = vt + (long)(b * NKV + kvh) * 128 * SL;

  for (int kt = 0; kt <= qblk; ++kt) {
    __syncthreads();
#pragma unroll
    for (int i = 0; i < 4; ++i) {   // K: 64 rows x 256B
      int c = tid + 256 * i;
      int row = c >> 4, slot = (c & 15) << 4;
      gload16(kbase + (long)(kt * 64 + row) * 128 + (((slot ^ ((row & 7) << 4))) >> 1), Ks + c * 16);
    }
#pragma unroll
    for (int i = 0; i < 4; ++i) {   // VT: 128 rows x 128B
      int c = tid + 256 * i;
      int row = c >> 3, slot = (c & 7) << 4;
      gload16(vbase + (long)row * SL + kt * 64 + (((slot ^ ((row & 7) << 4))) >> 1), Vs + c * 16);
    }
    asm volatile("s_waitcnt vmcnt(0)" ::: "memory");
    __syncthreads();

    // S = Q K^T (16x64 per wave)
    f32x4 sv[4];
#pragma unroll
    for (int n = 0; n < 4; ++n) {
      f32x4 z = {0.f, 0.f, 0.f, 0.f};
#pragma unroll
      for (int kk = 0; kk < 4; ++kk) {
        int row = n * 16 + lr;
        s16x8 kf = *(const s16x8*)(Ks + row * 256 + (((kk * 32 + lg * 8) * 2) ^ ((row & 7) << 4)));
        z = __builtin_amdgcn_mfma_f32_16x16x32_bf16(qf[kk], kf, z, 0, 0, 0);
      }
      sv[n] = z;
    }

    const float scale = 0.08838834764831845f;  // 1/sqrt(128)
    const bool diag = (kt == qblk);
    float mx[4];
#pragma unroll
    for (int r = 0; r < 4; ++r) mx[r] = -1e30f;
#pragma unroll
    for (int n = 0; n < 4; ++n)
#pragma unroll
      for (int r = 0; r < 4; ++r) {
        float v = sv[n][r] * scale;
        if (diag) {
          int colA = kt * 64 + n * 16 + lr;
          int rowA = qblk * 64 + w * 16 + lg * 4 + r;
          if (colA > rowA) v = -1e30f;
        }
        sv[n][r] = v;
        mx[r] = fmaxf(mx[r], v);
      }
#pragma unroll
    for (int r = 0; r < 4; ++r) {
      float v = mx[r];
      v = fmaxf(v, __shfl_xor(v, 1));
      v = fmaxf(v, __shfl_xor(v, 2));
      v = fmaxf(v, __shfl_xor(v, 4));
      v = fmaxf(v, __shfl_xor(v, 8));
      mx[r] = v;
    }
    float alpha[4];
#pragma unroll
    for (int r = 0; r < 4; ++r) {
      float mn = fmaxf(m_run[r], mx[r]);
      alpha[r] = __expf(m_run[r] - mn);
      m_run[r] = mn;
    }
    float rsum[4] = {0.f, 0.f, 0.f, 0.f};
#pragma unroll
    for (int n = 0; n < 4; ++n)
#pragma unroll
      for (int r = 0; r < 4; ++r) {
        float p = __expf(sv[n][r] - m_run[r]);
        sv[n][r] = p;
        rsum[r] += p;
      }
#pragma unroll
    for (int r = 0; r < 4; ++r) {
      float v = rsum[r];
      v += __shfl_xor(v, 1);
      v += __shfl_xor(v, 2);
      v += __shfl_xor(v, 4);
      v += __shfl_xor(v, 8);
      l_run[r] = l_run[r] * alpha[r] + v;
    }
#pragma unroll
    for (int n = 0; n < 8; ++n) {
      f32x4 a = acc[n];
#pragma unroll
      for (int r = 0; r < 4; ++r) a[r] *= alpha[r];
      acc[n] = a;
    }
    // P -> LDS (bf16, swizzled); own-wave rows only
#pragma unroll
    for (int n = 0; n < 4; ++n)
#pragma unroll
      for (int r = 0; r < 4; ++r) {
        int row = w * 16 + lg * 4 + r;
        int colB = (n * 16 + lr) * 2;
        *(u16*)(Ps + row * 128 + (colB ^ ((row & 7) << 4))) = f2bf(sv[n][r]);
      }
    // PV
#pragma unroll
    for (int kk = 0; kk < 2; ++kk) {
      int prow = w * 16 + lr;
      s16x8 pa = *(const s16x8*)(Ps + prow * 128 + (((kk * 32 + lg * 8) * 2) ^ ((prow & 7) << 4)));
#pragma unroll
      for (int n = 0; n < 8; ++n) {
        int vrow = n * 16 + lr;
        s16x8 vf = *(const s16x8*)(Vs + vrow * 128 + (((kk * 32 + lg * 8) * 2) ^ ((vrow & 7) << 4)));
        acc[n] = __builtin_amdgcn_mfma_f32_16x16x32_bf16(pa, vf, acc[n], 0, 0, 0);
      }
    }
  }

  float inv_l[4];
#pragma unroll
  for (int r = 0; r < 4; ++r) inv_l[r] = 1.0f / l_run[r];
  float* yp = yg + ((long)bh * SL + qblk * 64 + w * 16 + lg * 4) * 128;
#pragma unroll
  for (int n = 0; n < 8; ++n)
#pragma unroll
    for (int r = 0; r < 4; ++r)
      yp[(long)r * 128 + n * 16 + lr] = acc[n][r] * inv_l[r];
}

// ---------------- epilogue: y = yg - (yg.vn)vn, -> yb bf16 [token][dim] ----------------
__global__ __launch_bounds__(256) void epi(const float* __restrict__ yg,
                                           const float* __restrict__ qkv,
                                           u16* __restrict__ yb) {
  __shared__ float vn[4][128];
  int token = blockIdx.x;
  int b = token >> 11, t = token & (SL - 1);
  int lane = threadIdx.x & 63, w = threadIdx.x >> 6;
  const float* vp = qkv + (long)token * 3072 + 2560 + w * 128;
  float v0 = vp[lane], v1 = vp[lane + 64];
  float ss = v0 * v0 + v1 * v1;
  for (int m = 1; m < 64; m <<= 1) ss += __shfl_xor(ss, m);
  float inv = 1.0f / fmaxf(sqrtf(ss), 1e-12f);
  vn[w][lane] = v0 * inv;
  vn[w][lane + 64] = v1 * inv;
  __syncthreads();
  for (int hi = 0; hi < 4; ++hi) {
    int h = w * 4 + hi;  // kvh == w
    const float* yp = yg + ((long)(b * NH + h) * SL + t) * 128;
    float y0 = yp[lane], y1 = yp[lane + 64];
    float n0 = vn[w][lane], n1 = vn[w][lane + 64];
    float d = y0 * n0 + y1 * n1;
    for (int m = 1; m < 64; m <<= 1) d += __shfl_xor(d, m);
    y0 -= d * n0;
    y1 -= d * n1;
    u16* dst = yb + (long)token * DM + h * 128;
    dst[lane] = f2bf(y0);
    dst[lane + 64] = f2bf(y1);
  }
}

extern "C" void kernel_launch(void* const* d_in, const int* in_sizes, int n_in,
                              void* d_out, int out_size, void* d_ws, size_t ws_size,
                              hipStream_t stream) {
  const float* x  = (const float*)d_in[0];
  const float* Wq = (const float*)d_in[1];
  const float* Wk = (const float*)d_in[2];
  const float* Wv = (const float*)d_in[3];
  const float* Wo = (const float*)d_in[4];
  const float* qg = (const float*)d_in[5];
  float* out = (float*)d_out;

  char* p = (char*)d_ws;
  u16* xb   = (u16*)p;   p += (size_t)4096 * 2048 * 2;
  u16* WT   = (u16*)p;   p += (size_t)3072 * 2048 * 2;
  u16* WoT  = (u16*)p;   p += (size_t)2048 * 2048 * 2;
  float* qkv = (float*)p; p += (size_t)4096 * 3072 * 4;
  float* rc = (float*)p; p += (size_t)2048 * 64 * 4;
  float* rs = (float*)p; p += (size_t)2048 * 64 * 4;
  u16* qbuf = (u16*)p;   p += (size_t)NB * NH * SL * 128 * 2;
  u16* kbuf = (u16*)p;   p += (size_t)NB * NKV * SL * 128 * 2;
  u16* vtb  = (u16*)p;   p += (size_t)NB * NKV * 128 * SL * 2;
  float* yg = (float*)p; p += (size_t)NB * NH * SL * 128 * 4;
  u16* yb = xb;  // alias: xb dead after qkv GEMM

  cvt_x<<<4096, 256, 0, stream>>>(x, xb);
  wtrans<<<dim3(32, 32), 256, 0, stream>>>(Wq, WT, 2048, 2048);
  wtrans<<<dim3(8, 32), 256, 0, stream>>>(Wk, WT + (size_t)2048 * 2048, 2048, 512);
  wtrans<<<dim3(8, 32), 256, 0, stream>>>(Wv, WT + (size_t)2560 * 2048, 2048, 512);
  wtrans<<<dim3(32, 32), 256, 0, stream>>>(Wo, WoT, 2048, 2048);
  rope_tab<<<512, 256, 0, stream>>>(rc, rs);
  gemm_bt<<<dim3(32, 24), 256, 0, stream>>>(xb, WT, qkv, 4096, 3072, 2048);
  normrope<<<4096, 256, 0, stream>>>(qkv, rc, rs, qg, qbuf, kbuf);
  vtrans<<<256, 256, 0, stream>>>(qkv, vtb);
  attn<<<dim3(32, 32), 256, 0, stream>>>(qbuf, kbuf, vtb, yg);
  epi<<<4096, 256, 0, stream>>>(yg, qkv, yb);
  gemm_bt<<<dim3(32, 16), 256, 0, stream>>>(yb, WoT, out, 4096, 2048, 2048);
}

// Round 2
// 268.164 us; speedup vs baseline: 1.3192x; 1.3192x over previous
//
#include <hip/hip_runtime.h>

constexpr int SL  = 2048;
constexpr int NB  = 2;
constexpr int NH  = 16;
constexpr int NKV = 4;
constexpr int HDIM = 128;
constexpr int DM  = 2048;

typedef unsigned short u16;
typedef unsigned int   u32;
typedef short s16x8 __attribute__((ext_vector_type(8)));
typedef float f32x4 __attribute__((ext_vector_type(4)));

__device__ inline u16 f2bf(float x) {
  union { float f; u32 u; } c; c.f = x;
  u32 r = c.u + 0x7fffu + ((c.u >> 16) & 1u);
  return (u16)(r >> 16);
}

__device__ inline void gload16(const void* g, void* l) {
  __builtin_amdgcn_global_load_lds((const __attribute__((address_space(1))) void*)g,
                                   (__attribute__((address_space(3))) void*)l, 16, 0, 0);
}

// ---------------- x f32 -> bf16 ----------------
__global__ __launch_bounds__(256) void cvt_x(const float* __restrict__ x, u16* __restrict__ xb) {
  long i = ((long)blockIdx.x * 256 + threadIdx.x) * 8;
  float4 a = *(const float4*)(x + i);
  float4 b = *(const float4*)(x + i + 4);
  uint4 ov;
  ov.x = (u32)f2bf(a.x) | ((u32)f2bf(a.y) << 16);
  ov.y = (u32)f2bf(a.z) | ((u32)f2bf(a.w) << 16);
  ov.z = (u32)f2bf(b.x) | ((u32)f2bf(b.y) << 16);
  ov.w = (u32)f2bf(b.z) | ((u32)f2bf(b.w) << 16);
  *(uint4*)(xb + i) = ov;
}

// ---------------- weight transpose f32 KxN -> bf16 NxK ----------------
__global__ __launch_bounds__(256) void wtrans(const float* __restrict__ src, u16* __restrict__ dst,
                                              int K, int N) {
  __shared__ float ld[64][65];
  int tid = threadIdx.x;
  long c0 = (long)blockIdx.x * 64;
  long r0 = (long)blockIdx.y * 64;
  for (int i = 0; i < 16; ++i) {
    int e = tid + 256 * i;
    int r = e >> 6, c = e & 63;
    ld[r][c] = src[(r0 + r) * N + c0 + c];
  }
  __syncthreads();
  for (int i = 0; i < 16; ++i) {
    int e = tid + 256 * i;
    int r = e >> 6, c = e & 63;
    dst[(c0 + r) * K + r0 + c] = f2bf(ld[c][r]);
  }
}

// ---------------- rope tables ----------------
__global__ void rope_tab(float* __restrict__ rc, float* __restrict__ rs) {
  int i = blockIdx.x * 256 + threadIdx.x;
  int t = i >> 6, f = i & 63;
  float inv = expf(-(float)f * (9.210340371976184f / 64.0f));
  float ang = (float)t * inv;
  rc[i] = cosf(ang);
  rs[i] = sinf(ang);
}

// ---------------- GEMM: C[M][N] f32 = A[M][K]bf16 * BT[N][K]bf16^T ----------------
__global__ __launch_bounds__(256) void gemm_bt(const u16* __restrict__ A,
                                               const u16* __restrict__ BT,
                                               float* __restrict__ C,
                                               int M, int N, int K) {
  __shared__ __align__(16) char As[128 * 128];
  __shared__ __align__(16) char Bs[128 * 128];
  const int tid = threadIdx.x;
  const int lane = tid & 63;
  const int w = tid >> 6;
  const int wm = w >> 1, wn = w & 1;
  const int lr = lane & 15, lg = lane >> 4;
  const long bm = (long)blockIdx.x * 128;
  const long bn = (long)blockIdx.y * 128;

  f32x4 acc[4][4] = {};

  for (int kt = 0; kt < K; kt += 64) {
    __syncthreads();
#pragma unroll
    for (int i = 0; i < 4; ++i) {
      int c = tid + 256 * i;
      int row = c >> 3;
      int slot = (c & 7) << 4;
      int gs = slot ^ ((row & 7) << 4);
      gload16(A + (bm + row) * K + kt + (gs >> 1), As + c * 16);
    }
#pragma unroll
    for (int i = 0; i < 4; ++i) {
      int c = tid + 256 * i;
      int row = c >> 3;
      int slot = (c & 7) << 4;
      int gs = slot ^ ((row & 7) << 4);
      gload16(BT + (bn + row) * K + kt + (gs >> 1), Bs + c * 16);
    }
    asm volatile("s_waitcnt vmcnt(0)" ::: "memory");
    __syncthreads();

#pragma unroll
    for (int kk = 0; kk < 2; ++kk) {
      int colB = (kk * 32 + lg * 8) * 2;
      s16x8 af[4], bfv[4];
#pragma unroll
      for (int m = 0; m < 4; ++m) {
        int row = wm * 64 + m * 16 + lr;
        af[m] = *(const s16x8*)(As + row * 128 + (colB ^ ((row & 7) << 4)));
      }
#pragma unroll
      for (int n = 0; n < 4; ++n) {
        int row = wn * 64 + n * 16 + lr;
        bfv[n] = *(const s16x8*)(Bs + row * 128 + (colB ^ ((row & 7) << 4)));
      }
#pragma unroll
      for (int m = 0; m < 4; ++m)
#pragma unroll
        for (int n = 0; n < 4; ++n)
          acc[m][n] = __builtin_amdgcn_mfma_f32_16x16x32_bf16(af[m], bfv[n], acc[m][n], 0, 0, 0);
    }
  }

#pragma unroll
  for (int m = 0; m < 4; ++m)
#pragma unroll
    for (int n = 0; n < 4; ++n) {
      long row = bm + wm * 64 + m * 16 + lg * 4;
      long col = bn + wn * 64 + n * 16 + lr;
      float* cp = C + row * N + col;
#pragma unroll
      for (int r = 0; r < 4; ++r) cp[(long)r * N] = acc[m][n][r];
    }
}

// ---------------- RMSNorm + RoPE + gain (q pre-scaled by 1/sqrt(HD)) ----------------
__global__ __launch_bounds__(256) void normrope(const float* __restrict__ qkv,
                                                const float* __restrict__ rc,
                                                const float* __restrict__ rs,
                                                const float* __restrict__ qg,
                                                u16* __restrict__ qb, u16* __restrict__ kb) {
  int token = blockIdx.x;
  int b = token >> 11, t = token & (SL - 1);
  int lane = threadIdx.x & 63, w = threadIdx.x >> 6;
  const float* row = qkv + (long)token * 3072;
  float c = rc[t * 64 + lane], s = rs[t * 64 + lane];
  for (int slot = w; slot < 20; slot += 4) {
    const float* p = row + slot * 128;
    float v0 = p[lane], v1 = p[lane + 64];
    float ss = v0 * v0 + v1 * v1;
    for (int m = 1; m < 64; m <<= 1) ss += __shfl_xor(ss, m);
    float rms = rsqrtf(ss * (1.0f / 128.0f) + 1.1920929e-07f);
    v0 *= rms; v1 *= rms;
    float o0 =  v0 * c + v1 * s;
    float o1 = -v0 * s + v1 * c;
    u16* dst;
    if (slot < 16) {
      float g = qg[slot] * 0.08838834764831845f;  // fold attention scale
      o0 *= g; o1 *= g;
      dst = qb + ((long)(b * NH + slot) * SL + t) * 128;
    } else {
      dst = kb + ((long)(b * NKV + (slot - 16)) * SL + t) * 128;
    }
    dst[lane] = f2bf(o0);
    dst[lane + 64] = f2bf(o1);
  }
}

// ---------------- V transpose ----------------
__global__ __launch_bounds__(256) void vtrans(const float* __restrict__ qkv, u16* __restrict__ vt) {
  __shared__ float ld[64][129];
  int blk = blockIdx.x;
  int tt = blk & 31, kvb = blk >> 5;
  int tid = threadIdx.x;
  const float* src = qkv + (long)(((kvb >> 2) * SL) + tt * 64) * 3072 + 2560 + (kvb & 3) * 128;
  for (int i = 0; i < 32; ++i) {
    int e = tid + 256 * i;
    int r = e >> 7, d = e & 127;
    ld[r][d] = src[(long)r * 3072 + d];
  }
  __syncthreads();
  u16* dst = vt + (long)kvb * 128 * SL + tt * 64;
  for (int i = 0; i < 32; ++i) {
    int o = tid + 256 * i;
    int d = o >> 6, r = o & 63;
    dst[(long)d * SL + r] = f2bf(ld[r][d]);
  }
}

// ---------------- flash attention (causal, GQA) ----------------
// grid (16, 32): block x handles q-tiles {x, 31-x} sequentially (33 KV-iters each,
// uniform). Double-buffered K/V LDS, counted vmcnt pipeline (T3/T4), setprio (T5).
__global__ __launch_bounds__(256) void attn(const u16* __restrict__ qb, const u16* __restrict__ kb,
                                            const u16* __restrict__ vt, float* __restrict__ yg) {
  __shared__ __align__(16) char Ks[2][64 * 256];
  __shared__ __align__(16) char Vs[2][128 * 128];
  __shared__ __align__(16) char Ps[64 * 128];
  const int tid = threadIdx.x, lane = tid & 63, w = tid >> 6;
  const int pairIdx = blockIdx.x;
  const int bh = blockIdx.y;
  const int b = bh >> 4, h = bh & 15;
  const int kvh = h >> 2;
  const int lr = lane & 15, lg = lane >> 4;

  const u16* kbase = kb + (long)(b * NKV + kvh) * SL * 128;
  const u16* vbase = vt + (long)(b * NKV + kvh) * 128 * SL;

#pragma unroll 1
  for (int pass = 0; pass < 2; ++pass) {
    const int qblk = pass ? 31 - pairIdx : pairIdx;
    const int ntile = qblk + 1;

    const u16* qp = qb + ((long)bh * SL + qblk * 64 + w * 16 + lr) * 128;
    s16x8 qf[4];
#pragma unroll
    for (int kk = 0; kk < 4; ++kk) qf[kk] = *(const s16x8*)(qp + kk * 32 + lg * 8);

    f32x4 acc[8] = {};
    float m_run[4], l_run[4];
#pragma unroll
    for (int r = 0; r < 4; ++r) { m_run[r] = -1e30f; l_run[r] = 0.f; }

    // prologue: stage tile 0 into buffer 0
#pragma unroll
    for (int i = 0; i < 4; ++i) {
      int c = tid + 256 * i;
      int row = c >> 4, slot = (c & 15) << 4;
      gload16(kbase + (long)row * 128 + ((slot ^ ((row & 7) << 4)) >> 1), Ks[0] + c * 16);
    }
#pragma unroll
    for (int i = 0; i < 4; ++i) {
      int c = tid + 256 * i;
      int row = c >> 3, slot = (c & 7) << 4;
      gload16(vbase + (long)row * SL + ((slot ^ ((row & 7) << 4)) >> 1), Vs[0] + c * 16);
    }

#pragma unroll 1
    for (int kt = 0; kt < ntile; ++kt) {
      const int cur = kt & 1;
      if (kt + 1 < ntile) {
        // issue next tile's loads into the other buffer (stay in flight across barrier)
        const int nx = cur ^ 1;
#pragma unroll
        for (int i = 0; i < 4; ++i) {
          int c = tid + 256 * i;
          int row = c >> 4, slot = (c & 15) << 4;
          gload16(kbase + (long)((kt + 1) * 64 + row) * 128 + ((slot ^ ((row & 7) << 4)) >> 1),
                  Ks[nx] + c * 16);
        }
#pragma unroll
        for (int i = 0; i < 4; ++i) {
          int c = tid + 256 * i;
          int row = c >> 3, slot = (c & 7) << 4;
          gload16(vbase + (long)row * SL + (kt + 1) * 64 + ((slot ^ ((row & 7) << 4)) >> 1),
                  Vs[nx] + c * 16);
        }
        asm volatile("s_waitcnt vmcnt(8)" ::: "memory");  // current tile's 8 done; next 8 in flight
      } else {
        asm volatile("s_waitcnt vmcnt(0)" ::: "memory");
      }
      __builtin_amdgcn_s_barrier();

      // S = Q K^T (16x64 per wave)
      f32x4 sv[4];
      __builtin_amdgcn_s_setprio(1);
#pragma unroll
      for (int n = 0; n < 4; ++n) {
        f32x4 z = {0.f, 0.f, 0.f, 0.f};
#pragma unroll
        for (int kk = 0; kk < 4; ++kk) {
          int row = n * 16 + lr;
          s16x8 kf = *(const s16x8*)(Ks[cur] + row * 256 + (((kk * 32 + lg * 8) * 2) ^ ((row & 7) << 4)));
          z = __builtin_amdgcn_mfma_f32_16x16x32_bf16(qf[kk], kf, z, 0, 0, 0);
        }
        sv[n] = z;
      }
      __builtin_amdgcn_s_setprio(0);

      const bool diag = (kt == qblk);
      float mx[4];
#pragma unroll
      for (int r = 0; r < 4; ++r) mx[r] = -1e30f;
#pragma unroll
      for (int n = 0; n < 4; ++n)
#pragma unroll
        for (int r = 0; r < 4; ++r) {
          float v = sv[n][r];
          if (diag) {
            int colA = n * 16 + lr;
            int rowA = w * 16 + lg * 4 + r;
            if (colA > rowA) v = -1e30f;
          }
          sv[n][r] = v;
          mx[r] = fmaxf(mx[r], v);
        }
#pragma unroll
      for (int r = 0; r < 4; ++r) {
        float v = mx[r];
        v = fmaxf(v, __shfl_xor(v, 1));
        v = fmaxf(v, __shfl_xor(v, 2));
        v = fmaxf(v, __shfl_xor(v, 4));
        v = fmaxf(v, __shfl_xor(v, 8));
        mx[r] = v;
      }
      float alpha[4];
#pragma unroll
      for (int r = 0; r < 4; ++r) {
        float mn = fmaxf(m_run[r], mx[r]);
        alpha[r] = __expf(m_run[r] - mn);
        m_run[r] = mn;
      }
      float rsum[4] = {0.f, 0.f, 0.f, 0.f};
#pragma unroll
      for (int n = 0; n < 4; ++n)
#pragma unroll
        for (int r = 0; r < 4; ++r) {
          float p = __expf(sv[n][r] - m_run[r]);
          sv[n][r] = p;
          rsum[r] += p;
        }
#pragma unroll
      for (int r = 0; r < 4; ++r) {
        float v = rsum[r];
        v += __shfl_xor(v, 1);
        v += __shfl_xor(v, 2);
        v += __shfl_xor(v, 4);
        v += __shfl_xor(v, 8);
        l_run[r] = l_run[r] * alpha[r] + v;
      }
#pragma unroll
      for (int n = 0; n < 8; ++n) {
        f32x4 a = acc[n];
#pragma unroll
        for (int r = 0; r < 4; ++r) a[r] *= alpha[r];
        acc[n] = a;
      }
      // P -> LDS (wave-private rows, swizzled)
#pragma unroll
      for (int n = 0; n < 4; ++n)
#pragma unroll
        for (int r = 0; r < 4; ++r) {
          int row = w * 16 + lg * 4 + r;
          int colB = (n * 16 + lr) * 2;
          *(u16*)(Ps + row * 128 + (colB ^ ((row & 7) << 4))) = f2bf(sv[n][r]);
        }
      // PV
      __builtin_amdgcn_s_setprio(1);
#pragma unroll
      for (int kk = 0; kk < 2; ++kk) {
        int prow = w * 16 + lr;
        s16x8 pa = *(const s16x8*)(Ps + prow * 128 + (((kk * 32 + lg * 8) * 2) ^ ((prow & 7) << 4)));
#pragma unroll
        for (int n = 0; n < 8; ++n) {
          int vrow = n * 16 + lr;
          s16x8 vf = *(const s16x8*)(Vs[cur] + vrow * 128 + (((kk * 32 + lg * 8) * 2) ^ ((vrow & 7) << 4)));
          acc[n] = __builtin_amdgcn_mfma_f32_16x16x32_bf16(pa, vf, acc[n], 0, 0, 0);
        }
      }
      __builtin_amdgcn_s_setprio(0);
      __builtin_amdgcn_s_barrier();
    }

    float inv_l[4];
#pragma unroll
    for (int r = 0; r < 4; ++r) inv_l[r] = 1.0f / l_run[r];
    float* yp = yg + ((long)bh * SL + qblk * 64 + w * 16 + lg * 4) * 128;
#pragma unroll
    for (int n = 0; n < 8; ++n)
#pragma unroll
      for (int r = 0; r < 4; ++r)
        yp[(long)r * 128 + n * 16 + lr] = acc[n][r] * inv_l[r];
  }
}

// ---------------- epilogue: y = yg - (yg.vn)vn ----------------
__global__ __launch_bounds__(256) void epi(const float* __restrict__ yg,
                                           const float* __restrict__ qkv,
                                           u16* __restrict__ yb) {
  __shared__ float vn[4][128];
  int token = blockIdx.x;
  int b = token >> 11, t = token & (SL - 1);
  int lane = threadIdx.x & 63, w = threadIdx.x >> 6;
  const float* vp = qkv + (long)token * 3072 + 2560 + w * 128;
  float v0 = vp[lane], v1 = vp[lane + 64];
  float ss = v0 * v0 + v1 * v1;
  for (int m = 1; m < 64; m <<= 1) ss += __shfl_xor(ss, m);
  float inv = 1.0f / fmaxf(sqrtf(ss), 1e-12f);
  vn[w][lane] = v0 * inv;
  vn[w][lane + 64] = v1 * inv;
  __syncthreads();
  for (int hi = 0; hi < 4; ++hi) {
    int h = w * 4 + hi;
    const float* yp = yg + ((long)(b * NH + h) * SL + t) * 128;
    float y0 = yp[lane], y1 = yp[lane + 64];
    float n0 = vn[w][lane], n1 = vn[w][lane + 64];
    float d = y0 * n0 + y1 * n1;
    for (int m = 1; m < 64; m <<= 1) d += __shfl_xor(d, m);
    y0 -= d * n0;
    y1 -= d * n1;
    u16* dst = yb + (long)token * DM + h * 128;
    dst[lane] = f2bf(y0);
    dst[lane + 64] = f2bf(y1);
  }
}

extern "C" void kernel_launch(void* const* d_in, const int* in_sizes, int n_in,
                              void* d_out, int out_size, void* d_ws, size_t ws_size,
                              hipStream_t stream) {
  const float* x  = (const float*)d_in[0];
  const float* Wq = (const float*)d_in[1];
  const float* Wk = (const float*)d_in[2];
  const float* Wv = (const float*)d_in[3];
  const float* Wo = (const float*)d_in[4];
  const float* qg = (const float*)d_in[5];
  float* out = (float*)d_out;

  char* p = (char*)d_ws;
  u16* xb   = (u16*)p;   p += (size_t)4096 * 2048 * 2;
  u16* WT   = (u16*)p;   p += (size_t)3072 * 2048 * 2;
  u16* WoT  = (u16*)p;   p += (size_t)2048 * 2048 * 2;
  float* qkv = (float*)p; p += (size_t)4096 * 3072 * 4;
  float* rc = (float*)p; p += (size_t)2048 * 64 * 4;
  float* rs = (float*)p; p += (size_t)2048 * 64 * 4;
  u16* qbuf = (u16*)p;   p += (size_t)NB * NH * SL * 128 * 2;
  u16* kbuf = (u16*)p;   p += (size_t)NB * NKV * SL * 128 * 2;
  u16* vtb  = (u16*)p;   p += (size_t)NB * NKV * 128 * SL * 2;
  float* yg = (float*)p; p += (size_t)NB * NH * SL * 128 * 4;
  u16* yb = xb;

  cvt_x<<<4096, 256, 0, stream>>>(x, xb);
  wtrans<<<dim3(32, 32), 256, 0, stream>>>(Wq, WT, 2048, 2048);
  wtrans<<<dim3(8, 32), 256, 0, stream>>>(Wk, WT + (size_t)2048 * 2048, 2048, 512);
  wtrans<<<dim3(8, 32), 256, 0, stream>>>(Wv, WT + (size_t)2560 * 2048, 2048, 512);
  wtrans<<<dim3(32, 32), 256, 0, stream>>>(Wo, WoT, 2048, 2048);
  rope_tab<<<512, 256, 0, stream>>>(rc, rs);
  gemm_bt<<<dim3(32, 24), 256, 0, stream>>>(xb, WT, qkv, 4096, 3072, 2048);
  normrope<<<4096, 256, 0, stream>>>(qkv, rc, rs, qg, qbuf, kbuf);
  vtrans<<<256, 256, 0, stream>>>(qkv, vtb);
  attn<<<dim3(16, 32), 256, 0, stream>>>(qbuf, kbuf, vtb, yg);
  epi<<<4096, 256, 0, stream>>>(yg, qkv, yb);
  gemm_bt<<<dim3(32, 16), 256, 0, stream>>>(yb, WoT, out, 4096, 2048, 2048);
}

// Round 3
// 257.761 us; speedup vs baseline: 1.3725x; 1.0404x over previous
//
#include <hip/hip_runtime.h>

constexpr int SL  = 2048;
constexpr int NB  = 2;
constexpr int NH  = 16;
constexpr int NKV = 4;
constexpr int HDIM = 128;
constexpr int DM  = 2048;

typedef unsigned short u16;
typedef unsigned int   u32;
typedef short s16x8 __attribute__((ext_vector_type(8)));
typedef float f32x4 __attribute__((ext_vector_type(4)));

__device__ inline u16 f2bf(float x) {
  union { float f; u32 u; } c; c.f = x;
  u32 r = c.u + 0x7fffu + ((c.u >> 16) & 1u);
  return (u16)(r >> 16);
}
__device__ inline float bf2f(u16 h) {
  union { u32 u; float f; } c; c.u = ((u32)h) << 16; return c.f;
}

__device__ inline void gload16(const void* g, void* l) {
  __builtin_amdgcn_global_load_lds((const __attribute__((address_space(1))) void*)g,
                                   (__attribute__((address_space(3))) void*)l, 16, 0, 0);
}

// ---------------- x f32 -> bf16 ----------------
__global__ __launch_bounds__(256) void cvt_x(const float* __restrict__ x, u16* __restrict__ xb) {
  long i = ((long)blockIdx.x * 256 + threadIdx.x) * 8;
  float4 a = *(const float4*)(x + i);
  float4 b = *(const float4*)(x + i + 4);
  uint4 ov;
  ov.x = (u32)f2bf(a.x) | ((u32)f2bf(a.y) << 16);
  ov.y = (u32)f2bf(a.z) | ((u32)f2bf(a.w) << 16);
  ov.z = (u32)f2bf(b.x) | ((u32)f2bf(b.y) << 16);
  ov.w = (u32)f2bf(b.z) | ((u32)f2bf(b.w) << 16);
  *(uint4*)(xb + i) = ov;
}

// ---------------- weight transpose f32 KxN -> bf16 NxK ----------------
__global__ __launch_bounds__(256) void wtrans(const float* __restrict__ src, u16* __restrict__ dst,
                                              int K, int N) {
  __shared__ float ld[64][65];
  int tid = threadIdx.x;
  long c0 = (long)blockIdx.x * 64;
  long r0 = (long)blockIdx.y * 64;
  for (int i = 0; i < 16; ++i) {
    int e = tid + 256 * i;
    int r = e >> 6, c = e & 63;
    ld[r][c] = src[(r0 + r) * N + c0 + c];
  }
  __syncthreads();
  for (int i = 0; i < 16; ++i) {
    int e = tid + 256 * i;
    int r = e >> 6, c = e & 63;
    dst[(c0 + r) * K + r0 + c] = f2bf(ld[c][r]);
  }
}

// ---------------- rope tables ----------------
__global__ void rope_tab(float* __restrict__ rc, float* __restrict__ rs) {
  int i = blockIdx.x * 256 + threadIdx.x;
  int t = i >> 6, f = i & 63;
  float inv = expf(-(float)f * (9.210340371976184f / 64.0f));
  float ang = (float)t * inv;
  rc[i] = cosf(ang);
  rs[i] = sinf(ang);
}

// ---------------- GEMM: C[M][N] = A[M][K]bf16 * BT[N][K]^T, dbuf counted-vmcnt ----------------
template <int BF16OUT>
__global__ __launch_bounds__(256) void gemm_bt(const u16* __restrict__ A,
                                               const u16* __restrict__ BT,
                                               float* __restrict__ Cf,
                                               u16* __restrict__ Cb,
                                               int M, int N, int K) {
  __shared__ __align__(16) char As[2][128 * 128];
  __shared__ __align__(16) char Bs[2][128 * 128];
  const int tid = threadIdx.x;
  const int lane = tid & 63;
  const int w = tid >> 6;
  const int wm = w >> 1, wn = w & 1;
  const int lr = lane & 15, lg = lane >> 4;
  const long bm = (long)blockIdx.x * 128;
  const long bn = (long)blockIdx.y * 128;

  f32x4 acc[4][4] = {};

  auto stage = [&](int kt0, int buf) {
#pragma unroll
    for (int i = 0; i < 4; ++i) {
      int c = tid + 256 * i;
      int row = c >> 3;
      int slot = (c & 7) << 4;
      int gs = slot ^ ((row & 7) << 4);
      gload16(A + (bm + row) * K + kt0 + (gs >> 1), As[buf] + c * 16);
    }
#pragma unroll
    for (int i = 0; i < 4; ++i) {
      int c = tid + 256 * i;
      int row = c >> 3;
      int slot = (c & 7) << 4;
      int gs = slot ^ ((row & 7) << 4);
      gload16(BT + (bn + row) * K + kt0 + (gs >> 1), Bs[buf] + c * 16);
    }
  };

  const int nt = K >> 6;
  stage(0, 0);

#pragma unroll 1
  for (int ti = 0; ti < nt; ++ti) {
    const int cur = ti & 1;
    if (ti + 1 < nt) {
      stage((ti + 1) << 6, cur ^ 1);
      asm volatile("s_waitcnt vmcnt(8)" ::: "memory");
    } else {
      asm volatile("s_waitcnt vmcnt(0)" ::: "memory");
    }
    __builtin_amdgcn_s_barrier();

    __builtin_amdgcn_s_setprio(1);
#pragma unroll
    for (int kk = 0; kk < 2; ++kk) {
      int colB = (kk * 32 + lg * 8) * 2;
      s16x8 af[4], bfv[4];
#pragma unroll
      for (int m = 0; m < 4; ++m) {
        int row = wm * 64 + m * 16 + lr;
        af[m] = *(const s16x8*)(As[cur] + row * 128 + (colB ^ ((row & 7) << 4)));
      }
#pragma unroll
      for (int n = 0; n < 4; ++n) {
        int row = wn * 64 + n * 16 + lr;
        bfv[n] = *(const s16x8*)(Bs[cur] + row * 128 + (colB ^ ((row & 7) << 4)));
      }
#pragma unroll
      for (int m = 0; m < 4; ++m)
#pragma unroll
        for (int n = 0; n < 4; ++n)
          acc[m][n] = __builtin_amdgcn_mfma_f32_16x16x32_bf16(af[m], bfv[n], acc[m][n], 0, 0, 0);
    }
    __builtin_amdgcn_s_setprio(0);
    __builtin_amdgcn_s_barrier();
  }

#pragma unroll
  for (int m = 0; m < 4; ++m)
#pragma unroll
    for (int n = 0; n < 4; ++n) {
      long row = bm + wm * 64 + m * 16 + lg * 4;
      long col = bn + wn * 64 + n * 16 + lr;
#pragma unroll
      for (int r = 0; r < 4; ++r) {
        if (BF16OUT)
          Cb[(row + r) * N + col] = f2bf(acc[m][n][r]);
        else
          Cf[(row + r) * N + col] = acc[m][n][r];
      }
    }
}

// ---------------- RMSNorm + RoPE + gain (q pre-scaled by 1/sqrt(HD)); qkv in bf16 ----------------
__global__ __launch_bounds__(256) void normrope(const u16* __restrict__ qkv,
                                                const float* __restrict__ rc,
                                                const float* __restrict__ rs,
                                                const float* __restrict__ qg,
                                                u16* __restrict__ qb, u16* __restrict__ kb) {
  int token = blockIdx.x;
  int b = token >> 11, t = token & (SL - 1);
  int lane = threadIdx.x & 63, w = threadIdx.x >> 6;
  const u16* row = qkv + (long)token * 3072;
  float c = rc[t * 64 + lane], s = rs[t * 64 + lane];
  for (int slot = w; slot < 20; slot += 4) {
    const u16* p = row + slot * 128;
    float v0 = bf2f(p[lane]), v1 = bf2f(p[lane + 64]);
    float ss = v0 * v0 + v1 * v1;
    for (int m = 1; m < 64; m <<= 1) ss += __shfl_xor(ss, m);
    float rms = rsqrtf(ss * (1.0f / 128.0f) + 1.1920929e-07f);
    v0 *= rms; v1 *= rms;
    float o0 =  v0 * c + v1 * s;
    float o1 = -v0 * s + v1 * c;
    u16* dst;
    if (slot < 16) {
      float g = qg[slot] * 0.08838834764831845f;
      o0 *= g; o1 *= g;
      dst = qb + ((long)(b * NH + slot) * SL + t) * 128;
    } else {
      dst = kb + ((long)(b * NKV + (slot - 16)) * SL + t) * 128;
    }
    dst[lane] = f2bf(o0);
    dst[lane + 64] = f2bf(o1);
  }
}

// ---------------- V transpose (bf16 in/out) ----------------
__global__ __launch_bounds__(256) void vtrans(const u16* __restrict__ qkv, u16* __restrict__ vt) {
  __shared__ u16 ld[64][136];
  int blk = blockIdx.x;
  int tt = blk & 31, kvb = blk >> 5;
  int tid = threadIdx.x;
  const u16* src = qkv + (long)(((kvb >> 2) * SL) + tt * 64) * 3072 + 2560 + (kvb & 3) * 128;
  for (int i = 0; i < 32; ++i) {
    int e = tid + 256 * i;
    int r = e >> 7, d = e & 127;
    ld[r][d] = src[(long)r * 3072 + d];
  }
  __syncthreads();
  u16* dst = vt + (long)kvb * 128 * SL + tt * 64;
  for (int i = 0; i < 32; ++i) {
    int o = tid + 256 * i;
    int d = o >> 6, r = o & 63;
    dst[(long)d * SL + r] = ld[r][d];
  }
}

// ---------------- flash attention (causal, GQA) ----------------
__global__ __launch_bounds__(256) void attn(const u16* __restrict__ qb, const u16* __restrict__ kb,
                                            const u16* __restrict__ vt, u16* __restrict__ yg) {
  __shared__ __align__(16) char Ks[2][64 * 256];
  __shared__ __align__(16) char Vs[2][128 * 128];
  __shared__ __align__(16) char Ps[64 * 128];
  const int tid = threadIdx.x, lane = tid & 63, w = tid >> 6;
  const int pairIdx = blockIdx.x;
  const int bh = blockIdx.y;
  const int b = bh >> 4, h = bh & 15;
  const int kvh = h >> 2;
  const int lr = lane & 15, lg = lane >> 4;

  const u16* kbase = kb + (long)(b * NKV + kvh) * SL * 128;
  const u16* vbase = vt + (long)(b * NKV + kvh) * 128 * SL;

#pragma unroll 1
  for (int pass = 0; pass < 2; ++pass) {
    const int qblk = pass ? 31 - pairIdx : pairIdx;
    const int ntile = qblk + 1;

    const u16* qp = qb + ((long)bh * SL + qblk * 64 + w * 16 + lr) * 128;
    s16x8 qf[4];
#pragma unroll
    for (int kk = 0; kk < 4; ++kk) qf[kk] = *(const s16x8*)(qp + kk * 32 + lg * 8);

    f32x4 acc[8] = {};
    float m_run[4], l_run[4];
#pragma unroll
    for (int r = 0; r < 4; ++r) { m_run[r] = -1e30f; l_run[r] = 0.f; }

    // prologue: stage tile 0 into buffer 0 (Ks swizzle spans 16 slots; Vs 8)
#pragma unroll
    for (int i = 0; i < 4; ++i) {
      int c = tid + 256 * i;
      int row = c >> 4, slot = (c & 15) << 4;
      gload16(kbase + (long)row * 128 + ((slot ^ ((row & 15) << 4)) >> 1), Ks[0] + c * 16);
    }
#pragma unroll
    for (int i = 0; i < 4; ++i) {
      int c = tid + 256 * i;
      int row = c >> 3, slot = (c & 7) << 4;
      gload16(vbase + (long)row * SL + ((slot ^ ((row & 7) << 4)) >> 1), Vs[0] + c * 16);
    }

#pragma unroll 1
    for (int kt = 0; kt < ntile; ++kt) {
      const int cur = kt & 1;
      if (kt + 1 < ntile) {
        const int nx = cur ^ 1;
#pragma unroll
        for (int i = 0; i < 4; ++i) {
          int c = tid + 256 * i;
          int row = c >> 4, slot = (c & 15) << 4;
          gload16(kbase + (long)((kt + 1) * 64 + row) * 128 + ((slot ^ ((row & 15) << 4)) >> 1),
                  Ks[nx] + c * 16);
        }
#pragma unroll
        for (int i = 0; i < 4; ++i) {
          int c = tid + 256 * i;
          int row = c >> 3, slot = (c & 7) << 4;
          gload16(vbase + (long)row * SL + (kt + 1) * 64 + ((slot ^ ((row & 7) << 4)) >> 1),
                  Vs[nx] + c * 16);
        }
        asm volatile("s_waitcnt vmcnt(8)" ::: "memory");
      } else {
        asm volatile("s_waitcnt vmcnt(0)" ::: "memory");
      }
      __builtin_amdgcn_s_barrier();

      // S = Q K^T (16x64 per wave)
      f32x4 sv[4];
      __builtin_amdgcn_s_setprio(1);
#pragma unroll
      for (int n = 0; n < 4; ++n) {
        f32x4 z = {0.f, 0.f, 0.f, 0.f};
#pragma unroll
        for (int kk = 0; kk < 4; ++kk) {
          int row = n * 16 + lr;
          s16x8 kf = *(const s16x8*)(Ks[cur] + row * 256 + (((kk * 32 + lg * 8) * 2) ^ ((row & 15) << 4)));
          z = __builtin_amdgcn_mfma_f32_16x16x32_bf16(qf[kk], kf, z, 0, 0, 0);
        }
        sv[n] = z;
      }
      __builtin_amdgcn_s_setprio(0);

      const bool diag = (kt == qblk);
      float mx[4];
#pragma unroll
      for (int r = 0; r < 4; ++r) mx[r] = -1e30f;
#pragma unroll
      for (int n = 0; n < 4; ++n)
#pragma unroll
        for (int r = 0; r < 4; ++r) {
          float v = sv[n][r];
          if (diag) {
            int colA = n * 16 + lr;
            int rowA = w * 16 + lg * 4 + r;
            if (colA > rowA) v = -1e30f;
          }
          sv[n][r] = v;
          mx[r] = fmaxf(mx[r], v);
        }
#pragma unroll
      for (int r = 0; r < 4; ++r) {
        float v = mx[r];
        v = fmaxf(v, __shfl_xor(v, 1));
        v = fmaxf(v, __shfl_xor(v, 2));
        v = fmaxf(v, __shfl_xor(v, 4));
        v = fmaxf(v, __shfl_xor(v, 8));
        mx[r] = v;
      }
      // T13 defer-max: skip rescale when max growth <= 8 across all rows
      bool okb = true;
#pragma unroll
      for (int r = 0; r < 4; ++r) okb = okb && (mx[r] <= m_run[r] + 8.0f);
      if (!__all(okb ? 1 : 0)) {
        float alpha[4];
#pragma unroll
        for (int r = 0; r < 4; ++r) {
          float mn = fmaxf(m_run[r], mx[r]);
          alpha[r] = __expf(m_run[r] - mn);
          m_run[r] = mn;
          l_run[r] *= alpha[r];
        }
#pragma unroll
        for (int n = 0; n < 8; ++n) {
          f32x4 a = acc[n];
#pragma unroll
          for (int r = 0; r < 4; ++r) a[r] *= alpha[r];
          acc[n] = a;
        }
      }
      float rsum[4] = {0.f, 0.f, 0.f, 0.f};
#pragma unroll
      for (int n = 0; n < 4; ++n)
#pragma unroll
        for (int r = 0; r < 4; ++r) {
          float p = __expf(sv[n][r] - m_run[r]);
          sv[n][r] = p;
          rsum[r] += p;
        }
#pragma unroll
      for (int r = 0; r < 4; ++r) {
        float v = rsum[r];
        v += __shfl_xor(v, 1);
        v += __shfl_xor(v, 2);
        v += __shfl_xor(v, 4);
        v += __shfl_xor(v, 8);
        l_run[r] += v;
      }
      // P -> LDS (wave-private rows, swizzled)
#pragma unroll
      for (int n = 0; n < 4; ++n)
#pragma unroll
        for (int r = 0; r < 4; ++r) {
          int row = w * 16 + lg * 4 + r;
          int colB = (n * 16 + lr) * 2;
          *(u16*)(Ps + row * 128 + (colB ^ ((row & 7) << 4))) = f2bf(sv[n][r]);
        }
      // PV
      __builtin_amdgcn_s_setprio(1);
#pragma unroll
      for (int kk = 0; kk < 2; ++kk) {
        int prow = w * 16 + lr;
        s16x8 pa = *(const s16x8*)(Ps + prow * 128 + (((kk * 32 + lg * 8) * 2) ^ ((prow & 7) << 4)));
#pragma unroll
        for (int n = 0; n < 8; ++n) {
          int vrow = n * 16 + lr;
          s16x8 vf = *(const s16x8*)(Vs[cur] + vrow * 128 + (((kk * 32 + lg * 8) * 2) ^ ((vrow & 7) << 4)));
          acc[n] = __builtin_amdgcn_mfma_f32_16x16x32_bf16(pa, vf, acc[n], 0, 0, 0);
        }
      }
      __builtin_amdgcn_s_setprio(0);
      __builtin_amdgcn_s_barrier();
    }

    float inv_l[4];
#pragma unroll
    for (int r = 0; r < 4; ++r) inv_l[r] = 1.0f / l_run[r];
    u16* yp = yg + ((long)bh * SL + qblk * 64 + w * 16 + lg * 4) * 128;
#pragma unroll
    for (int n = 0; n < 8; ++n)
#pragma unroll
      for (int r = 0; r < 4; ++r)
        yp[(long)r * 128 + n * 16 + lr] = f2bf(acc[n][r] * inv_l[r]);
  }
}

// ---------------- epilogue: y = yg - (yg.vn)vn (bf16 in/out) ----------------
__global__ __launch_bounds__(256) void epi(const u16* __restrict__ yg,
                                           const u16* __restrict__ qkv,
                                           u16* __restrict__ yb) {
  __shared__ float vn[4][128];
  int token = blockIdx.x;
  int b = token >> 11, t = token & (SL - 1);
  int lane = threadIdx.x & 63, w = threadIdx.x >> 6;
  const u16* vp = qkv + (long)token * 3072 + 2560 + w * 128;
  float v0 = bf2f(vp[lane]), v1 = bf2f(vp[lane + 64]);
  float ss = v0 * v0 + v1 * v1;
  for (int m = 1; m < 64; m <<= 1) ss += __shfl_xor(ss, m);
  float inv = 1.0f / fmaxf(sqrtf(ss), 1e-12f);
  vn[w][lane] = v0 * inv;
  vn[w][lane + 64] = v1 * inv;
  __syncthreads();
  for (int hi = 0; hi < 4; ++hi) {
    int h = w * 4 + hi;
    const u16* yp = yg + ((long)(b * NH + h) * SL + t) * 128;
    float y0 = bf2f(yp[lane]), y1 = bf2f(yp[lane + 64]);
    float n0 = vn[w][lane], n1 = vn[w][lane + 64];
    float d = y0 * n0 + y1 * n1;
    for (int m = 1; m < 64; m <<= 1) d += __shfl_xor(d, m);
    y0 -= d * n0;
    y1 -= d * n1;
    u16* dst = yb + (long)token * DM + h * 128;
    dst[lane] = f2bf(y0);
    dst[lane + 64] = f2bf(y1);
  }
}

extern "C" void kernel_launch(void* const* d_in, const int* in_sizes, int n_in,
                              void* d_out, int out_size, void* d_ws, size_t ws_size,
                              hipStream_t stream) {
  const float* x  = (const float*)d_in[0];
  const float* Wq = (const float*)d_in[1];
  const float* Wk = (const float*)d_in[2];
  const float* Wv = (const float*)d_in[3];
  const float* Wo = (const float*)d_in[4];
  const float* qg = (const float*)d_in[5];
  float* out = (float*)d_out;

  char* p = (char*)d_ws;
  u16* xb    = (u16*)p;   p += (size_t)4096 * 2048 * 2;
  u16* WT    = (u16*)p;   p += (size_t)3072 * 2048 * 2;
  u16* WoT   = (u16*)p;   p += (size_t)2048 * 2048 * 2;
  u16* qkvb  = (u16*)p;   p += (size_t)4096 * 3072 * 2;
  float* rc  = (float*)p; p += (size_t)2048 * 64 * 4;
  float* rs  = (float*)p; p += (size_t)2048 * 64 * 4;
  u16* qbuf  = (u16*)p;   p += (size_t)NB * NH * SL * 128 * 2;
  u16* kbuf  = (u16*)p;   p += (size_t)NB * NKV * SL * 128 * 2;
  u16* vtb   = (u16*)p;   p += (size_t)NB * NKV * 128 * SL * 2;
  u16* ygb   = (u16*)p;   p += (size_t)NB * NH * SL * 128 * 2;
  u16* yb = xb;  // alias: xb dead after qkv GEMM

  cvt_x<<<4096, 256, 0, stream>>>(x, xb);
  wtrans<<<dim3(32, 32), 256, 0, stream>>>(Wq, WT, 2048, 2048);
  wtrans<<<dim3(8, 32), 256, 0, stream>>>(Wk, WT + (size_t)2048 * 2048, 2048, 512);
  wtrans<<<dim3(8, 32), 256, 0, stream>>>(Wv, WT + (size_t)2560 * 2048, 2048, 512);
  wtrans<<<dim3(32, 32), 256, 0, stream>>>(Wo, WoT, 2048, 2048);
  rope_tab<<<512, 256, 0, stream>>>(rc, rs);
  gemm_bt<1><<<dim3(32, 24), 256, 0, stream>>>(xb, WT, nullptr, qkvb, 4096, 3072, 2048);
  normrope<<<4096, 256, 0, stream>>>(qkvb, rc, rs, qg, qbuf, kbuf);
  vtrans<<<256, 256, 0, stream>>>(qkvb, vtb);
  attn<<<dim3(16, 32), 256, 0, stream>>>(qbuf, kbuf, vtb, ygb);
  epi<<<4096, 256, 0, stream>>>(ygb, qkvb, yb);
  gemm_bt<0><<<dim3(32, 16), 256, 0, stream>>>(yb, WoT, out, nullptr, 4096, 2048, 2048);
}